// Round 3
// baseline (562.463 us; speedup 1.0000x reference)
//
#include <hip/hip_runtime.h>
#include <math.h>

#define N_NODES 100000
#define E_EDGES 1600000
#define D_IN    128
#define H_MID   32
#define C_OUT   5

#define BSHIFT 8
#define BNODES 256    // nodes per dst-bucket
#define NBKT   391    // ceil(100000/256)
#define BCAP   4500   // per-bucket staging cap (mean 4092, +6.4 sigma)
#define SRC_BITS 17
#define SRC_MASK 0x1FFFF
#define EB     4096   // edges per binA block

#define KP   136      // LDS k-stride in bf16 units (x-tile)
#define ACCP 33       // padded accumulator col stride (breaks bank alignment)

typedef __attribute__((ext_vector_type(8))) short bf16x8;
typedef __attribute__((ext_vector_type(4))) float f32x4;

// round-to-nearest-even fp32 -> bf16 bits
__device__ inline unsigned f2bf(float f) {
    unsigned u = __float_as_uint(f);
    return (u + 0x7FFFu + ((u >> 16) & 1u)) >> 16;
}

__device__ inline float bflo(unsigned v) { return __uint_as_float((v & 0xFFFFu) << 16); }
__device__ inline float bfhi(unsigned v) { return __uint_as_float(v & 0xFFFF0000u); }

// ---------------- prep: zero cursors + build transposed bf16 W1 panel ------
__global__ void k_prep(const float* __restrict__ Wrel,
                       const float* __restrict__ Wroot,
                       int* __restrict__ bucket_cursor,
                       unsigned short* __restrict__ wt_g) {
    int tid = threadIdx.x;                 // 512
    bucket_cursor[tid] = 0;                // 512 >= NBKT
    for (int i = tid; i < 64 * 128; i += 512) {
        int n = i >> 7, k = i & 127;
        float v = (n < H_MID) ? Wrel[k * H_MID + n] : Wroot[k * H_MID + (n - H_MID)];
        wt_g[i] = (unsigned short)f2bf(v);   // wt_g[n][k]
    }
}

// ---------------- K1 (MFMA): [xrel|xroot] = x @ [Wrel|Wroot] ----------------
__global__ __launch_bounds__(256) void k1_mfma(
    const float* __restrict__ x,
    const unsigned short* __restrict__ wt_g,
    const float* __restrict__ b1,
    unsigned short* __restrict__ xrelh,
    float* __restrict__ xroot) {
    __shared__ unsigned short xs[64 * KP];
    int tid = threadIdx.x;
    int nodeBase = blockIdx.x * 64;

    #pragma unroll
    for (int it = 0; it < 16; ++it) {
        int idx = it * 256 + tid;          // row*64 + kpair
        int row = idx >> 6, kp = idx & 63;
        int node = nodeBase + row;
        float2 v = make_float2(0.f, 0.f);
        if (node < N_NODES)
            v = *(const float2*)(x + (size_t)node * D_IN + kp * 2);
        unsigned pk = f2bf(v.x) | (f2bf(v.y) << 16);
        *(unsigned*)(xs + row * KP + kp * 2) = pk;
    }
    __syncthreads();

    int lane = tid & 63;
    int wv = tid >> 6;
    int m = lane & 15;
    int quad = lane >> 4;

    f32x4 acc[4];
    #pragma unroll
    for (int nt = 0; nt < 4; ++nt) acc[nt] = (f32x4){0.f, 0.f, 0.f, 0.f};

    #pragma unroll
    for (int kk = 0; kk < 4; ++kk) {
        int k0 = kk * 32 + quad * 8;
        bf16x8 a = *(const bf16x8*)(xs + (wv * 16 + m) * KP + k0);
        #pragma unroll
        for (int nt = 0; nt < 4; ++nt) {
            bf16x8 b = *(const bf16x8*)(wt_g + (nt * 16 + m) * 128 + k0);
            acc[nt] = __builtin_amdgcn_mfma_f32_16x16x32_bf16(a, b, acc[nt], 0, 0, 0);
        }
    }

    #pragma unroll
    for (int nt = 0; nt < 4; ++nt) {
        #pragma unroll
        for (int r = 0; r < 4; ++r) {
            int node = nodeBase + wv * 16 + quad * 4 + r;
            int colg = nt * 16 + m;
            if (node < N_NODES) {
                if (colg < H_MID) {
                    xrelh[(size_t)node * H_MID + colg] =
                        (unsigned short)f2bf(acc[nt][r]);
                } else {
                    int c = colg - H_MID;
                    xroot[(size_t)node * H_MID + c] = acc[nt][r] + b1[c];
                }
            }
        }
    }
}

// -------- binA: counting-sort 4096 edges by dst-bucket in LDS --------------
// staged element: int2 { (dstLow8 << 17) | src17 , w_bits }  (8 B/edge)
__global__ __launch_bounds__(1024) void k_binA(
    const int* __restrict__ src,
    const int* __restrict__ dst,
    const float* __restrict__ ew,
    int* __restrict__ bucket_cursor,
    int2* __restrict__ staged) {
    __shared__ int cnt[NBKT];
    __shared__ int lstart[NBKT];
    __shared__ int gbase[NBKT];
    __shared__ int scanbuf[512];
    __shared__ int2 ebuf[EB];
    __shared__ short bbuf[EB];
    int tid = threadIdx.x;
    int eBase = blockIdx.x * EB;

    if (tid < NBKT) cnt[tid] = 0;
    __syncthreads();

    int b[4], rank[4], packed[4], wbits[4];
    bool valid[4];
    #pragma unroll
    for (int u = 0; u < 4; ++u) {
        int e = eBase + u * 1024 + tid;
        valid[u] = (e < E_EDGES);
        b[u] = 0; rank[u] = 0; packed[u] = 0; wbits[u] = 0;
        if (valid[u]) {
            int d = dst[e];
            int s = src[e];
            wbits[u] = __float_as_int(ew[e]);
            b[u] = d >> BSHIFT;
            packed[u] = ((d & (BNODES - 1)) << SRC_BITS) | s;
            rank[u] = atomicAdd(&cnt[b[u]], 1);
        }
    }
    __syncthreads();

    if (tid < 512) scanbuf[tid] = (tid < NBKT) ? cnt[tid] : 0;
    __syncthreads();
    for (int off = 1; off < 512; off <<= 1) {
        int t = 0;
        if (tid < 512 && tid >= off) t = scanbuf[tid - off];
        __syncthreads();
        if (tid < 512) scanbuf[tid] += t;
        __syncthreads();
    }
    if (tid < NBKT) {
        lstart[tid] = scanbuf[tid] - cnt[tid];
        gbase[tid]  = atomicAdd(&bucket_cursor[tid], cnt[tid]);
    }
    __syncthreads();
    int total = scanbuf[NBKT - 1];

    #pragma unroll
    for (int u = 0; u < 4; ++u) {
        if (valid[u]) {
            int slot = lstart[b[u]] + rank[u];
            ebuf[slot] = make_int2(packed[u], wbits[u]);
            bbuf[slot] = (short)b[u];
        }
    }
    __syncthreads();

    for (int t = tid; t < total; t += 1024) {
        int2 ev = ebuf[t];
        int bb = bbuf[t];
        int gpos = gbase[bb] + (t - lstart[bb]);
        if (gpos < BCAP)
            staged[(size_t)bb * BCAP + gpos] = ev;
    }
}

// -------- Layer 1, bucket-parallel LDS accumulate (no sorted CSR) ----------
// 1 block = 1 bucket (256 nodes). 64 groups of 16 lanes; 4 edges/group/round.
// acc[256][33] f32 in LDS via ds_add_f32; deg via LDS histogram.
__global__ __launch_bounds__(1024) void k_layer1B(
    const int* __restrict__ bucket_cursor,
    const int2* __restrict__ staged,
    const unsigned short* __restrict__ xrelh,
    const float* __restrict__ xroot,
    const float* __restrict__ Wrel2,
    const float* __restrict__ Wroot2,
    const float* __restrict__ b2,
    float* __restrict__ h2rel,
    float* __restrict__ h2root) {
    __shared__ float acc[BNODES * ACCP];   // 33.8 KB
    __shared__ int hist[BNODES];
    int tid = threadIdx.x;
    int b = blockIdx.x;

    for (int i = tid; i < BNODES * ACCP; i += 1024) acc[i] = 0.f;
    if (tid < BNODES) hist[tid] = 0;
    __syncthreads();

    int count = bucket_cursor[b];
    if (count > BCAP) count = BCAP;
    const int2* sp = staged + (size_t)b * BCAP;

    int g = tid >> 4;                      // 0..63
    int lane = tid & 15;                   // cols 2*lane, 2*lane+1

    int nb = count >> 8;                   // full 256-edge rounds
    for (int r = 0; r < nb; ++r) {
        int i = (r << 8) + (g << 2);
        int2 e0 = sp[i], e1 = sp[i + 1], e2 = sp[i + 2], e3 = sp[i + 3];
        unsigned v0 = *(const unsigned*)(xrelh + (size_t)(e0.x & SRC_MASK) * H_MID + lane * 2);
        unsigned v1 = *(const unsigned*)(xrelh + (size_t)(e1.x & SRC_MASK) * H_MID + lane * 2);
        unsigned v2 = *(const unsigned*)(xrelh + (size_t)(e2.x & SRC_MASK) * H_MID + lane * 2);
        unsigned v3 = *(const unsigned*)(xrelh + (size_t)(e3.x & SRC_MASK) * H_MID + lane * 2);
        int d0 = ((unsigned)e0.x) >> SRC_BITS;
        int d1 = ((unsigned)e1.x) >> SRC_BITS;
        int d2 = ((unsigned)e2.x) >> SRC_BITS;
        int d3 = ((unsigned)e3.x) >> SRC_BITS;
        float w0 = __int_as_float(e0.y);
        float w1 = __int_as_float(e1.y);
        float w2 = __int_as_float(e2.y);
        float w3 = __int_as_float(e3.y);
        atomicAdd(&acc[d0 * ACCP + 2 * lane],     bflo(v0) * w0);
        atomicAdd(&acc[d0 * ACCP + 2 * lane + 1], bfhi(v0) * w0);
        atomicAdd(&acc[d1 * ACCP + 2 * lane],     bflo(v1) * w1);
        atomicAdd(&acc[d1 * ACCP + 2 * lane + 1], bfhi(v1) * w1);
        atomicAdd(&acc[d2 * ACCP + 2 * lane],     bflo(v2) * w2);
        atomicAdd(&acc[d2 * ACCP + 2 * lane + 1], bfhi(v2) * w2);
        atomicAdd(&acc[d3 * ACCP + 2 * lane],     bflo(v3) * w3);
        atomicAdd(&acc[d3 * ACCP + 2 * lane + 1], bfhi(v3) * w3);
        if (lane == 0) {
            atomicAdd(&hist[d0], 1);
            atomicAdd(&hist[d1], 1);
            atomicAdd(&hist[d2], 1);
            atomicAdd(&hist[d3], 1);
        }
    }
    for (int i = (nb << 8) + g; i < count; i += 64) {
        int2 e0 = sp[i];
        unsigned v0 = *(const unsigned*)(xrelh + (size_t)(e0.x & SRC_MASK) * H_MID + lane * 2);
        int d0 = ((unsigned)e0.x) >> SRC_BITS;
        float w0 = __int_as_float(e0.y);
        atomicAdd(&acc[d0 * ACCP + 2 * lane],     bflo(v0) * w0);
        atomicAdd(&acc[d0 * ACCP + 2 * lane + 1], bfhi(v0) * w0);
        if (lane == 0) atomicAdd(&hist[d0], 1);
    }
    __syncthreads();

    // epilogue: mean + root + relu + W2 projections; 16 lanes/node, 4 passes
    #pragma unroll
    for (int pass = 0; pass < 4; ++pass) {
        int nl = pass * 64 + (tid >> 4);
        int node = b * BNODES + nl;
        if (node < N_NODES) {
            int dg = hist[nl];
            float inv = 1.0f / fmaxf((float)dg, 1.0f);
            float a0 = acc[nl * ACCP + 2 * lane] * inv;
            float a1 = acc[nl * ACCP + 2 * lane + 1] * inv;
            float2 rt = *(const float2*)(xroot + (size_t)node * H_MID + lane * 2);
            float h0 = fmaxf(a0 + rt.x, 0.f);
            float h1 = fmaxf(a1 + rt.y, 0.f);

            float p[2 * C_OUT];
            #pragma unroll
            for (int j = 0; j < C_OUT; ++j) {
                p[j]         = h0 * Wrel2[(2 * lane) * C_OUT + j]
                             + h1 * Wrel2[(2 * lane + 1) * C_OUT + j];
                p[C_OUT + j] = h0 * Wroot2[(2 * lane) * C_OUT + j]
                             + h1 * Wroot2[(2 * lane + 1) * C_OUT + j];
            }
            #pragma unroll
            for (int mm = 8; mm > 0; mm >>= 1) {
                #pragma unroll
                for (int j = 0; j < 2 * C_OUT; ++j)
                    p[j] += __shfl_xor(p[j], mm, 16);
            }
            if (lane == 0) {
                #pragma unroll
                for (int j = 0; j < C_OUT; ++j) {
                    h2rel[(size_t)node * C_OUT + j]  = p[j];
                    h2root[(size_t)node * C_OUT + j] = p[C_OUT + j] + b2[j];
                }
            }
        }
    }
}

// -------- Layer 2, bucket-parallel LDS accumulate + log_softmax ------------
// 128 groups of 8 lanes; 4 edges/group/round; acc2[256][9] f32 + hist.
__global__ __launch_bounds__(1024) void k_layer2B(
    const int* __restrict__ bucket_cursor,
    const int2* __restrict__ staged,
    const float* __restrict__ h2rel,
    const float* __restrict__ h2root,
    float* __restrict__ out) {
    __shared__ float acc2[BNODES * 9];     // 9.2 KB
    __shared__ int hist[BNODES];
    int tid = threadIdx.x;
    int b = blockIdx.x;

    for (int i = tid; i < BNODES * 9; i += 1024) acc2[i] = 0.f;
    if (tid < BNODES) hist[tid] = 0;
    __syncthreads();

    int count = bucket_cursor[b];
    if (count > BCAP) count = BCAP;
    const int2* sp = staged + (size_t)b * BCAP;

    int g = tid >> 3;                      // 0..127
    int lane = tid & 7;

    int nb = count >> 9;                   // full 512-edge rounds
    for (int r = 0; r < nb; ++r) {
        int i = (r << 9) + (g << 2);
        int2 e0 = sp[i], e1 = sp[i + 1], e2 = sp[i + 2], e3 = sp[i + 3];
        int d0 = ((unsigned)e0.x) >> SRC_BITS;
        int d1 = ((unsigned)e1.x) >> SRC_BITS;
        int d2 = ((unsigned)e2.x) >> SRC_BITS;
        int d3 = ((unsigned)e3.x) >> SRC_BITS;
        if (lane < C_OUT) {
            float v0 = h2rel[(size_t)(e0.x & SRC_MASK) * C_OUT + lane];
            float v1 = h2rel[(size_t)(e1.x & SRC_MASK) * C_OUT + lane];
            float v2 = h2rel[(size_t)(e2.x & SRC_MASK) * C_OUT + lane];
            float v3 = h2rel[(size_t)(e3.x & SRC_MASK) * C_OUT + lane];
            atomicAdd(&acc2[d0 * 9 + lane], v0);
            atomicAdd(&acc2[d1 * 9 + lane], v1);
            atomicAdd(&acc2[d2 * 9 + lane], v2);
            atomicAdd(&acc2[d3 * 9 + lane], v3);
        }
        if (lane == 0) {
            atomicAdd(&hist[d0], 1);
            atomicAdd(&hist[d1], 1);
            atomicAdd(&hist[d2], 1);
            atomicAdd(&hist[d3], 1);
        }
    }
    for (int i = (nb << 9) + g; i < count; i += 128) {
        int2 e0 = sp[i];
        int d0 = ((unsigned)e0.x) >> SRC_BITS;
        if (lane < C_OUT) {
            float v0 = h2rel[(size_t)(e0.x & SRC_MASK) * C_OUT + lane];
            atomicAdd(&acc2[d0 * 9 + lane], v0);
        }
        if (lane == 0) atomicAdd(&hist[d0], 1);
    }
    __syncthreads();

    // epilogue: mean + root + log_softmax; 8 lanes/node, 2 passes
    #pragma unroll
    for (int pass = 0; pass < 2; ++pass) {
        int nl = pass * 128 + (tid >> 3);
        int node = b * BNODES + nl;
        if (node < N_NODES) {
            int dg = hist[nl];
            float inv = 1.0f / fmaxf((float)dg, 1.0f);
            float o = (lane < C_OUT)
                          ? acc2[nl * 9 + lane] * inv + h2root[(size_t)node * C_OUT + lane]
                          : -INFINITY;
            float m = o;
            #pragma unroll
            for (int dd = 4; dd > 0; dd >>= 1) m = fmaxf(m, __shfl_xor(m, dd, 8));
            float e = (lane < C_OUT) ? expf(o - m) : 0.f;
            float ssum = e;
            #pragma unroll
            for (int dd = 4; dd > 0; dd >>= 1) ssum += __shfl_xor(ssum, dd, 8);
            float lse = m + logf(ssum);
            if (lane < C_OUT)
                out[(size_t)node * C_OUT + lane] = o - lse;
        }
    }
}

extern "C" void kernel_launch(void* const* d_in, const int* in_sizes, int n_in,
                              void* d_out, int out_size, void* d_ws, size_t ws_size,
                              hipStream_t stream) {
    const float* x      = (const float*)d_in[0];
    const int*   ei     = (const int*)d_in[1];
    const float* ew     = (const float*)d_in[2];
    const float* Wrel1  = (const float*)d_in[3];
    const float* Wroot1 = (const float*)d_in[4];
    const float* b1     = (const float*)d_in[5];
    const float* Wrel2  = (const float*)d_in[6];
    const float* Wroot2 = (const float*)d_in[7];
    const float* b2     = (const float*)d_in[8];
    float* out = (float*)d_out;

    const int* src = ei;
    const int* dst = ei + E_EDGES;

    // Workspace layout (no aliasing; staged lives until k_layer2B).
    // cursor 2KB + wt 16KB + staged 14.08MB + xrelh 6.4MB + xroot 12.8MB
    // + h2rel 2MB + h2root 2MB = 37.3MB total.
    char* ws = (char*)d_ws;
    int*   bucket_cursor = (int*)ws;                               // 512
    unsigned short* wt_g = (unsigned short*)(bucket_cursor + 512); // 64*128 bf16
    int2*  staged        = (int2*)(wt_g + 64 * 128);               // NBKT*BCAP
    unsigned short* xrelh = (unsigned short*)(staged + (size_t)NBKT * BCAP); // 32N
    float* xroot         = (float*)(xrelh + (size_t)N_NODES * H_MID);  // 32N f32
    float* h2rel         = xroot + (size_t)N_NODES * H_MID;        // 5N
    float* h2root        = h2rel + (size_t)N_NODES * C_OUT;        // 5N

    // --- prep: zero cursors + bf16 W panel ---
    k_prep<<<1, 512, 0, stream>>>(Wrel1, Wroot1, bucket_cursor, wt_g);

    // --- bucket binning (single pass; no intra-bucket sort needed) ---
    k_binA<<<(E_EDGES + EB - 1) / EB, 1024, 0, stream>>>(src, dst, ew,
                                                         bucket_cursor, staged);

    // --- dense projections via MFMA ---
    k1_mfma<<<(N_NODES + 63) / 64, 256, 0, stream>>>(x, wt_g, b1,
                                                     xrelh, xroot);

    // --- layer 1: bucket-parallel LDS accumulate + node update + W2 proj ---
    k_layer1B<<<NBKT, 1024, 0, stream>>>(bucket_cursor, staged,
                                         xrelh, xroot, Wrel2, Wroot2, b2,
                                         h2rel, h2root);

    // --- layer 2: bucket-parallel LDS accumulate + log_softmax ---
    k_layer2B<<<NBKT, 1024, 0, stream>>>(bucket_cursor, staged,
                                         h2rel, h2root, out);
}